// Round 5
// baseline (699.461 us; speedup 1.0000x reference)
//
#include <hip/hip_runtime.h>

#define Bq 2
#define Lq 1024
#define Dq 1024
#define Hq 16
#define HDq 64
#define HIDq 4096
#define Mq (Bq*Lq)   // 2048

typedef __bf16 bf16x8 __attribute__((ext_vector_type(8)));
typedef float floatx4 __attribute__((ext_vector_type(4)));

__device__ __forceinline__ float us2f(unsigned short u){
  unsigned v = ((unsigned)u) << 16;
  return __builtin_bit_cast(float, v);
}
__device__ __forceinline__ unsigned short f2us(float f){
  unsigned u = __builtin_bit_cast(unsigned, f);
  u = u + 0x7fffu + ((u >> 16) & 1u);      // RNE to bf16
  return (unsigned short)(u >> 16);
}

__device__ __forceinline__ void glds16(const unsigned short* g, unsigned short* l){
  __builtin_amdgcn_global_load_lds(
      (const __attribute__((address_space(1))) unsigned int*)g,
      (__attribute__((address_space(3))) unsigned int*)l, 16, 0, 0);
}

// ---------------- f32 -> bf16 conversion (weights), 4 arrays per launch ----------------
__global__ __launch_bounds__(256) void cvt4_kernel(
    const float* __restrict__ s0, const float* __restrict__ s1,
    const float* __restrict__ s2, const float* __restrict__ s3,
    unsigned short* __restrict__ d0, unsigned short* __restrict__ d1,
    unsigned short* __restrict__ d2, unsigned short* __restrict__ d3,
    int n)
{
  const int a = blockIdx.y;
  const float* s = (a==0) ? s0 : (a==1) ? s1 : (a==2) ? s2 : s3;
  unsigned short* d = (a==0) ? d0 : (a==1) ? d1 : (a==2) ? d2 : d3;
  const int i = (blockIdx.x * 256 + threadIdx.x) * 8;
  if (i >= n) return;
  float4 v0 = ((const float4*)(s + i))[0];
  float4 v1 = ((const float4*)(s + i))[1];
  ushort4 o0, o1;
  o0.x=f2us(v0.x); o0.y=f2us(v0.y); o0.z=f2us(v0.z); o0.w=f2us(v0.w);
  o1.x=f2us(v1.x); o1.y=f2us(v1.y); o1.z=f2us(v1.z); o1.w=f2us(v1.w);
  ((ushort4*)(d + i))[0] = o0;
  ((ushort4*)(d + i))[1] = o1;
}

// ---------------- W1 -> W1cat [8192,2048]: row 2u=[Wr|-Wi], 2u+1=[Wi|Wr] ----------------
__global__ __launch_bounds__(256) void w1cat_kernel(
    const float* __restrict__ Wr, const float* __restrict__ Wi,   // [4096,1024]
    unsigned short* __restrict__ dst)
{
  const int tid = blockIdx.x*256 + threadIdx.x;   // 4096*128
  const int u = tid >> 7;
  const int k = (tid & 127) * 8;
  float4 r0 = *(const float4*)(Wr + (size_t)u*1024 + k);
  float4 r1 = *(const float4*)(Wr + (size_t)u*1024 + k + 4);
  float4 i0 = *(const float4*)(Wi + (size_t)u*1024 + k);
  float4 i1 = *(const float4*)(Wi + (size_t)u*1024 + k + 4);
  ushort4 R0 = {f2us(r0.x),f2us(r0.y),f2us(r0.z),f2us(r0.w)};
  ushort4 R1 = {f2us(r1.x),f2us(r1.y),f2us(r1.z),f2us(r1.w)};
  ushort4 I0 = {f2us(i0.x),f2us(i0.y),f2us(i0.z),f2us(i0.w)};
  ushort4 I1 = {f2us(i1.x),f2us(i1.y),f2us(i1.z),f2us(i1.w)};
  ushort4 N0 = {f2us(-i0.x),f2us(-i0.y),f2us(-i0.z),f2us(-i0.w)};
  ushort4 N1 = {f2us(-i1.x),f2us(-i1.y),f2us(-i1.z),f2us(-i1.w)};
  unsigned short* p0 = dst + (size_t)(2*u)*2048;
  unsigned short* p1 = dst + (size_t)(2*u+1)*2048;
  *(ushort4*)(p0 + k) = R0;          *(ushort4*)(p0 + k + 4) = R1;
  *(ushort4*)(p0 + 1024 + k) = N0;   *(ushort4*)(p0 + 1024 + k + 4) = N1;
  *(ushort4*)(p1 + k) = I0;          *(ushort4*)(p1 + k + 4) = I1;
  *(ushort4*)(p1 + 1024 + k) = R0;   *(ushort4*)(p1 + 1024 + k + 4) = R1;
}

// ---------------- W2 -> W2cat [2048,8192]: row n: k=2u->Wr,-Wi ; row 1024+n: Wi,Wr ----------------
__global__ __launch_bounds__(256) void w2cat_kernel(
    const float* __restrict__ Wr, const float* __restrict__ Wi,   // [1024,4096]
    unsigned short* __restrict__ dst)
{
  const int tid = blockIdx.x*256 + threadIdx.x;   // 1024*512
  const int n = tid >> 9;
  const int u = (tid & 511) * 8;
  float4 r0 = *(const float4*)(Wr + (size_t)n*4096 + u);
  float4 r1 = *(const float4*)(Wr + (size_t)n*4096 + u + 4);
  float4 i0 = *(const float4*)(Wi + (size_t)n*4096 + u);
  float4 i1 = *(const float4*)(Wi + (size_t)n*4096 + u + 4);
  unsigned short a[16], b[16];
  const float rr[8] = {r0.x,r0.y,r0.z,r0.w,r1.x,r1.y,r1.z,r1.w};
  const float ii[8] = {i0.x,i0.y,i0.z,i0.w,i1.x,i1.y,i1.z,i1.w};
  #pragma unroll
  for (int e=0;e<8;++e){
    a[2*e]   = f2us(rr[e]);  a[2*e+1] = f2us(-ii[e]);
    b[2*e]   = f2us(ii[e]);  b[2*e+1] = f2us(rr[e]);
  }
  unsigned short* p0 = dst + (size_t)n*8192 + 2*u;
  unsigned short* p1 = dst + (size_t)(1024+n)*8192 + 2*u;
  *(uint4*)(p0)     = *(const uint4*)&a[0];
  *(uint4*)(p0 + 8) = *(const uint4*)&a[8];
  *(uint4*)(p1)     = *(const uint4*)&b[0];
  *(uint4*)(p1 + 8) = *(const uint4*)&b[8];
}

// ---------------- complex LayerNorm: f32 in, bf16 out (ostride for augmented out) ----------------
__global__ __launch_bounds__(256) void cln_kernel(
    const float* __restrict__ xr, const float* __restrict__ xi,
    const float* __restrict__ gr, const float* __restrict__ gi,
    const float* __restrict__ br, const float* __restrict__ bi,
    unsigned short* __restrict__ outr, unsigned short* __restrict__ outi,
    int ostride)
{
  const int row = blockIdx.x;
  const int t = threadIdx.x;
  const int lane = t & 63, wv = t >> 6;
  __shared__ float sred[8];

  float4 v4r = ((const float4*)(xr + (size_t)row*Dq))[t];
  float4 v4i = ((const float4*)(xi + (size_t)row*Dq))[t];
  float vr[4] = {v4r.x, v4r.y, v4r.z, v4r.w};
  float vi[4] = {v4i.x, v4i.y, v4i.z, v4i.w};
  float sr = vr[0]+vr[1]+vr[2]+vr[3];
  float si = vi[0]+vi[1]+vi[2]+vi[3];
  #pragma unroll
  for (int o=32;o>0;o>>=1){ sr += __shfl_down(sr,o,64); si += __shfl_down(si,o,64); }
  if (lane==0){ sred[wv]=sr; sred[4+wv]=si; }
  __syncthreads();
  float mr = (sred[0]+sred[1]+sred[2]+sred[3]) * (1.0f/Dq);
  float mi = (sred[4]+sred[5]+sred[6]+sred[7]) * (1.0f/Dq);
  float cr[4], ci[4], vs = 0.f;
  #pragma unroll
  for (int j=0;j<4;++j){ cr[j]=vr[j]-mr; ci[j]=vi[j]-mi; vs += cr[j]*cr[j]+ci[j]*ci[j]; }
  #pragma unroll
  for (int o=32;o>0;o>>=1) vs += __shfl_down(vs,o,64);
  __syncthreads();
  if (lane==0) sred[wv]=vs;
  __syncthreads();
  float var = (sred[0]+sred[1]+sred[2]+sred[3]) * (1.0f/Dq);
  float inv = rsqrtf(var + 1e-6f);

  float4 g4r = ((const float4*)gr)[t];
  float4 g4i = ((const float4*)gi)[t];
  float4 b4r = ((const float4*)br)[t];
  float4 b4i = ((const float4*)bi)[t];
  float grf[4] = {g4r.x,g4r.y,g4r.z,g4r.w};
  float gif[4] = {g4i.x,g4i.y,g4i.z,g4i.w};
  float brf[4] = {b4r.x,b4r.y,b4r.z,b4r.w};
  float bif[4] = {b4i.x,b4i.y,b4i.z,b4i.w};
  ushort4 o_r, o_i;
  unsigned short orr[4], oii[4];
  #pragma unroll
  for (int j=0;j<4;++j){
    float nr = cr[j]*inv, ni = ci[j]*inv;
    orr[j] = f2us(nr*grf[j] - ni*gif[j] + brf[j]);
    oii[j] = f2us(nr*gif[j] + ni*grf[j] + bif[j]);
  }
  o_r.x=orr[0]; o_r.y=orr[1]; o_r.z=orr[2]; o_r.w=orr[3];
  o_i.x=oii[0]; o_i.y=oii[1]; o_i.z=oii[2]; o_i.w=oii[3];
  ((ushort4*)(outr + (size_t)row*ostride))[t] = o_r;
  ((ushort4*)(outi + (size_t)row*ostride))[t] = o_i;
}

// ---------------- complex GEMM (64x64 tile) — used for QKV (RoPE) and Wo ----------------
// EPI: 0 plain bf16; 1 +bias+resid(f32)->f32
template<int EPI, bool ROPE>
__global__ __launch_bounds__(256,2) void cgemm_kernel(
    const unsigned short* __restrict__ Ar, const unsigned short* __restrict__ Ai,
    const unsigned short* __restrict__ Wr, const unsigned short* __restrict__ Wi,
    void* __restrict__ Cr, void* __restrict__ Ci,
    const float* __restrict__ biasR, const float* __restrict__ biasI,
    const float* __restrict__ resR, const float* __restrict__ resI,
    int Ndim, int Kdim)
{
  const int t = threadIdx.x;
  const int wv = t >> 6, lane = t & 63;
  const int quad = lane >> 4, l15 = lane & 15;
  const int m0 = blockIdx.x * 64, n0 = blockIdx.y * 64;

  __shared__ __align__(16) unsigned short sAr[64*40], sAi[64*40], sWr[64*40], sWi[64*40];

  floatx4 accRR[4], accII[4], accRI[4], accIR[4];
  floatx4 zero = {0.f,0.f,0.f,0.f};
  #pragma unroll
  for (int i=0;i<4;++i){ accRR[i]=zero; accII[i]=zero; accRI[i]=zero; accIR[i]=zero; }

  const int lr = t >> 2;
  const int lc = (t & 3) * 8;
  const unsigned short* pAr = Ar + (size_t)(m0+lr)*Kdim + lc;
  const unsigned short* pAi = Ai + (size_t)(m0+lr)*Kdim + lc;
  const unsigned short* pWr = Wr + (size_t)(n0+lr)*Kdim + lc;
  const unsigned short* pWi = Wi + (size_t)(n0+lr)*Kdim + lc;
  const int ldso = lr*40 + lc;
  const int arow = wv*16 + l15;

  const int nk = Kdim >> 5;
  for (int kk=0; kk<nk; ++kk){
    uint4 va = *(const uint4*)(pAr + kk*32);
    uint4 vb = *(const uint4*)(pAi + kk*32);
    uint4 vc = *(const uint4*)(pWr + kk*32);
    uint4 vd = *(const uint4*)(pWi + kk*32);
    __syncthreads();
    *(uint4*)&sAr[ldso] = va;
    *(uint4*)&sAi[ldso] = vb;
    *(uint4*)&sWr[ldso] = vc;
    *(uint4*)&sWi[ldso] = vd;
    __syncthreads();
    bf16x8 fAr = *(const bf16x8*)&sAr[arow*40 + quad*8];
    bf16x8 fAi = *(const bf16x8*)&sAi[arow*40 + quad*8];
    #pragma unroll
    for (int tt=0; tt<4; ++tt){
      const int brow = tt*16 + l15;
      bf16x8 fWr = *(const bf16x8*)&sWr[brow*40 + quad*8];
      bf16x8 fWi = *(const bf16x8*)&sWi[brow*40 + quad*8];
      accRR[tt] = __builtin_amdgcn_mfma_f32_16x16x32_bf16(fAr, fWr, accRR[tt], 0,0,0);
      accII[tt] = __builtin_amdgcn_mfma_f32_16x16x32_bf16(fAi, fWi, accII[tt], 0,0,0);
      accRI[tt] = __builtin_amdgcn_mfma_f32_16x16x32_bf16(fAr, fWi, accRI[tt], 0,0,0);
      accIR[tt] = __builtin_amdgcn_mfma_f32_16x16x32_bf16(fAi, fWr, accIR[tt], 0,0,0);
    }
  }

  float cr[4][4], ci[4][4];
  #pragma unroll
  for (int tt=0; tt<4; ++tt)
    #pragma unroll
    for (int r=0; r<4; ++r){
      cr[tt][r] = accRR[tt][r] - accII[tt][r];
      ci[tt][r] = accRI[tt][r] + accIR[tt][r];
    }

  if (ROPE){
    #pragma unroll
    for (int tt=0; tt<2; ++tt){
      const int j = tt*16 + l15;
      const float invf = powf(10000.0f, -(float)j * (1.0f/32.0f));
      #pragma unroll
      for (int r=0; r<4; ++r){
        const int gm = m0 + wv*16 + quad*4 + r;
        const int l = gm & (Lq-1);
        float s, c;
        sincosf((float)l * invf, &s, &c);
        float xr_ = cr[tt][r], yr_ = cr[tt+2][r];
        cr[tt][r]   = xr_*c - yr_*s;
        cr[tt+2][r] = yr_*c + xr_*s;
        float xi_ = ci[tt][r], yi_ = ci[tt+2][r];
        ci[tt][r]   = xi_*c - yi_*s;
        ci[tt+2][r] = yi_*c + xi_*s;
      }
    }
  }

  #pragma unroll
  for (int tt=0; tt<4; ++tt){
    const int gn = n0 + tt*16 + l15;
    float bR = 0.f, bI = 0.f;
    if (EPI >= 1){ bR = biasR[gn]; bI = biasI[gn]; }
    #pragma unroll
    for (int r=0; r<4; ++r){
      const int gm = m0 + wv*16 + quad*4 + r;
      const size_t idx = (size_t)gm*Ndim + gn;
      float vr_ = cr[tt][r] + bR, vi_ = ci[tt][r] + bI;
      if (EPI == 1){ vr_ += resR[idx]; vi_ += resI[idx]; }
      if (EPI == 0){
        ((unsigned short*)Cr)[idx] = f2us(vr_);
        ((unsigned short*)Ci)[idx] = f2us(vi_);
      } else {
        ((float*)Cr)[idx] = vr_;
        ((float*)Ci)[idx] = vi_;
      }
    }
  }
}

// ---------------- real GEMM (m97 structure): C[M,N] = A[M,K] @ W[N,K]^T ----------------
// BMt in {128,64}; BN=128; BK=32. frag-linear LDS + global_load_lds(16B).
// EPI 1: split-half f32 out + bias + resid; EPI 2: ModReLU on interleaved col pairs, bf16 out
template<int EPI, int BMt>
__global__ __launch_bounds__(256,2) void rgemm_kernel(
    const unsigned short* __restrict__ A,
    const unsigned short* __restrict__ W,
    void* __restrict__ C0, void* __restrict__ C1,
    const float* __restrict__ bias0, const float* __restrict__ bias1,
    const float* __restrict__ res0, const float* __restrict__ res1,
    const float* __restrict__ modb,
    int Ndim, int Kdim)
{
  constexpr int TA = BMt/32;          // acc row-subtiles per wave (4 or 2)
  constexpr int GA = BMt/16;          // A 16-row groups (8 or 4)
  constexpr int NC = (GA + 8) / 4;    // staging calls (4 or 3)
  const int t = threadIdx.x;
  const int w = t >> 6, lane = t & 63;
  const int wr = w >> 1, wc = w & 1;
  const int quad = lane >> 4, l15 = lane & 15;
  const int m0 = blockIdx.x * BMt, n0 = blockIdx.y * 128;

  __shared__ __align__(16) unsigned short sA[BMt*32];
  __shared__ __align__(16) unsigned short sW[128*32];

  floatx4 acc[TA][4];
  const floatx4 fzero = {0.f,0.f,0.f,0.f};
  #pragma unroll
  for (int ta=0; ta<TA; ++ta)
    #pragma unroll
    for (int tb=0; tb<4; ++tb) acc[ta][tb] = fzero;

  const int sl = lane & 15, sc8 = (lane >> 4) * 8;

  for (int kk = 0; kk < (Kdim >> 5); ++kk){
    const int k0 = kk*32;
    __syncthreads();
    #pragma unroll
    for (int c = 0; c < NC; ++c){
      const int cg = c*4 + w;
      if (cg < GA)
        glds16(A + (size_t)(m0 + cg*16 + sl)*Kdim + k0 + sc8, &sA[cg*512]);
      else
        glds16(W + (size_t)(n0 + (cg-GA)*16 + sl)*Kdim + k0 + sc8, &sW[(cg-GA)*512]);
    }
    __syncthreads();
    bf16x8 af[TA], wf[4];
    #pragma unroll
    for (int ta=0; ta<TA; ++ta) af[ta] = *(const bf16x8*)&sA[(wr*TA + ta)*512 + lane*8];
    #pragma unroll
    for (int tb=0; tb<4; ++tb)  wf[tb] = *(const bf16x8*)&sW[(wc*4 + tb)*512 + lane*8];
    #pragma unroll
    for (int ta=0; ta<TA; ++ta)
      #pragma unroll
      for (int tb=0; tb<4; ++tb)
        acc[ta][tb] = __builtin_amdgcn_mfma_f32_16x16x32_bf16(af[ta], wf[tb], acc[ta][tb], 0,0,0);
  }

  const int Nh = Ndim >> 1;
  #pragma unroll
  for (int ta=0; ta<TA; ++ta){
    #pragma unroll
    for (int tb=0; tb<4; ++tb){
      const int gn = n0 + wc*64 + tb*16 + l15;
      if (EPI == 1){
        const bool hi = gn >= Nh;
        const int col = hi ? gn - Nh : gn;
        const float bs = hi ? bias1[col] : bias0[col];
        const float* rp = hi ? res1 : res0;
        float* op = hi ? (float*)C1 : (float*)C0;
        #pragma unroll
        for (int r=0; r<4; ++r){
          const int gm = m0 + wr*(BMt/2) + ta*16 + quad*4 + r;
          op[(size_t)gm*Nh + col] = acc[ta][tb][r] + bs + rp[(size_t)gm*Nh + col];
        }
      } else {
        const int u = gn >> 1;
        const float bs = (gn & 1) ? bias1[u] : bias0[u];
        const float mb = modb[u];
        #pragma unroll
        for (int r=0; r<4; ++r){
          const int gm = m0 + wr*(BMt/2) + ta*16 + quad*4 + r;
          float v = acc[ta][tb][r] + bs;
          float p = __shfl_xor(v, 1, 64);
          float mag = sqrtf(v*v + p*p);
          float act = fmaxf(mag + mb, 0.f);
          float sc = act / (mag > 0.f ? mag : 1.f);
          ((unsigned short*)C0)[(size_t)gm*Ndim + gn] = f2us(v*sc);
        }
      }
    }
  }
}

// ---------------- V transpose: V[b,l,h*64+d] -> VT[(b*16+h)*64+d][l] ----------------
__global__ __launch_bounds__(256) void vtrans_kernel(
    const unsigned short* __restrict__ Vr, const unsigned short* __restrict__ Vi,
    unsigned short* __restrict__ VTr, unsigned short* __restrict__ VTi)
{
  const int lt = blockIdx.x;
  const int bh = blockIdx.y;
  const int h = bh & (Hq-1), b = bh >> 4;
  const int t = threadIdx.x;
  __shared__ unsigned short sTr[64*65], sTi[64*65];

  const int row = t >> 2;
  const int dc  = (t & 3) * 16;
  const size_t g = ((size_t)(b*Lq) + lt*64 + row)*Dq + h*HDq + dc;
  uint4 a0 = *(const uint4*)(Vr + g);
  uint4 a1 = *(const uint4*)(Vr + g + 8);
  uint4 b0 = *(const uint4*)(Vi + g);
  uint4 b1 = *(const uint4*)(Vi + g + 8);
  const unsigned short* pa0 = (const unsigned short*)&a0;
  const unsigned short* pa1 = (const unsigned short*)&a1;
  const unsigned short* pb0 = (const unsigned short*)&b0;
  const unsigned short* pb1 = (const unsigned short*)&b1;
  #pragma unroll
  for (int e=0;e<8;++e){
    sTr[(dc+e)*65 + row]   = pa0[e];
    sTr[(dc+8+e)*65 + row] = pa1[e];
    sTi[(dc+e)*65 + row]   = pb0[e];
    sTi[(dc+8+e)*65 + row] = pb1[e];
  }
  __syncthreads();
  const int d  = t >> 2;
  const int lc = (t & 3) * 16;
  unsigned short bufr[16], bufi[16];
  #pragma unroll
  for (int e=0;e<16;++e){
    bufr[e] = sTr[d*65 + lc + e];
    bufi[e] = sTi[d*65 + lc + e];
  }
  const size_t og = ((size_t)bh*HDq + d)*Lq + lt*64 + lc;
  *(uint4*)(VTr + og)     = *(const uint4*)&bufr[0];
  *(uint4*)(VTr + og + 8) = *(const uint4*)&bufr[8];
  *(uint4*)(VTi + og)     = *(const uint4*)&bufi[0];
  *(uint4*)(VTi + og + 8) = *(const uint4*)&bufi[8];
}

// ---------------- flash attention: 64x64 tiles, MFMA, online softmax ----------------
__device__ __forceinline__ int swz(int v){ return v ^ ((v >> 4) & 7); }

__global__ __launch_bounds__(256,2) void fattn_kernel(
    const unsigned short* __restrict__ Qr, const unsigned short* __restrict__ Qi,
    const unsigned short* __restrict__ Kr, const unsigned short* __restrict__ Ki,
    const unsigned short* __restrict__ VTr, const unsigned short* __restrict__ VTi,
    unsigned short* __restrict__ Or, unsigned short* __restrict__ Oi)
{
  const int qt = (int)(gridDim.x - 1 - blockIdx.x);
  const int bh = blockIdx.y;
  const int h = bh & (Hq-1), b = bh >> 4;
  const int t = threadIdx.x;
  const int w = t >> 6, lane = t & 63;
  const int quad = lane >> 4, l15 = lane & 15;

  __shared__ __align__(16) unsigned short sKr[4096], sKi[4096], sVr[4096], sVi[4096];
  __shared__ __align__(16) unsigned short sP[64*72];

  const size_t qbase = ((size_t)(b*Lq) + qt*64 + w*16 + l15)*Dq + h*HDq;
  bf16x8 qr_lo = *(const bf16x8*)(Qr + qbase + quad*8);
  bf16x8 qr_hi = *(const bf16x8*)(Qr + qbase + 32 + quad*8);
  bf16x8 qi_lo = *(const bf16x8*)(Qi + qbase + quad*8);
  bf16x8 qi_hi = *(const bf16x8*)(Qi + qbase + 32 + quad*8);

  const floatx4 fzero = {0.f,0.f,0.f,0.f};
  floatx4 aOr[4], aOi[4];
  #pragma unroll
  for (int i=0;i<4;++i){ aOr[i]=fzero; aOi[i]=fzero; }
  float m_run[4] = {-1e30f,-1e30f,-1e30f,-1e30f};
  float l_run[4] = {0.f,0.f,0.f,0.f};

  const int srow = t >> 2;
  const int sns  = srow >> 4;
  const int sl15 = srow & 15;
  const int q8   = (t & 3) * 2;
  const int dstA = sns*1024 + swz(q8*16 + sl15)*8;
  const int dstB = sns*1024 + swz((q8+1)*16 + sl15)*8;

  const int rd0 = swz(quad*16 + l15)*8;
  const int rd1 = swz((4+quad)*16 + l15)*8;

  for (int kt = 0; kt <= qt; ++kt){
    const size_t kg = ((size_t)(b*Lq) + kt*64 + srow)*Dq + h*HDq + q8*8;
    uint4 ka = *(const uint4*)(Kr + kg);
    uint4 kb = *(const uint4*)(Kr + kg + 8);
    uint4 kc = *(const uint4*)(Ki + kg);
    uint4 kd = *(const uint4*)(Ki + kg + 8);
    const size_t vg = ((size_t)bh*HDq + srow)*Lq + kt*64 + q8*8;
    uint4 va = *(const uint4*)(VTr + vg);
    uint4 vb = *(const uint4*)(VTr + vg + 8);
    uint4 vc = *(const uint4*)(VTi + vg);
    uint4 vd = *(const uint4*)(VTi + vg + 8);
    __syncthreads();
    *(uint4*)&sKr[dstA] = ka;  *(uint4*)&sKr[dstB] = kb;
    *(uint4*)&sKi[dstA] = kc;  *(uint4*)&sKi[dstB] = kd;
    *(uint4*)&sVr[dstA] = va;  *(uint4*)&sVr[dstB] = vb;
    *(uint4*)&sVi[dstA] = vc;  *(uint4*)&sVi[dstB] = vd;
    __syncthreads();

    floatx4 sc[4];
    #pragma unroll
    for (int ns=0; ns<4; ++ns){
      floatx4 x = fzero;
      x = __builtin_amdgcn_mfma_f32_16x16x32_bf16(qr_lo, *(const bf16x8*)&sKr[ns*1024 + rd0], x, 0,0,0);
      x = __builtin_amdgcn_mfma_f32_16x16x32_bf16(qr_hi, *(const bf16x8*)&sKr[ns*1024 + rd1], x, 0,0,0);
      x = __builtin_amdgcn_mfma_f32_16x16x32_bf16(qi_lo, *(const bf16x8*)&sKi[ns*1024 + rd0], x, 0,0,0);
      x = __builtin_amdgcn_mfma_f32_16x16x32_bf16(qi_hi, *(const bf16x8*)&sKi[ns*1024 + rd1], x, 0,0,0);
      sc[ns] = x;
    }

    const bool diag = (kt == qt);
    float rmax[4] = {-1e30f,-1e30f,-1e30f,-1e30f};
    #pragma unroll
    for (int ns=0; ns<4; ++ns){
      #pragma unroll
      for (int r=0; r<4; ++r){
        float s = sc[ns][r] * 0.125f;
        if (diag && (ns*16 + l15 > w*16 + quad*4 + r)) s = -1e30f;
        sc[ns][r] = s;
        rmax[r] = fmaxf(rmax[r], s);
      }
    }
    #pragma unroll
    for (int off=1; off<16; off<<=1){
      #pragma unroll
      for (int r=0; r<4; ++r) rmax[r] = fmaxf(rmax[r], __shfl_xor(rmax[r], off, 64));
    }

    float alpha[4], rsum[4];
    #pragma unroll
    for (int r=0; r<4; ++r){
      float mn = fmaxf(m_run[r], rmax[r]);
      alpha[r] = __expf(m_run[r] - mn);
      m_run[r] = mn;
      rsum[r] = 0.f;
    }
    #pragma unroll
    for (int ns=0; ns<4; ++ns){
      #pragma unroll
      for (int r=0; r<4; ++r){
        float p = __expf(sc[ns][r] - m_run[r]);
        rsum[r] += p;
        sP[(w*16 + quad*4 + r)*72 + ns*16 + l15] = f2us(p);
      }
    }
    #pragma unroll
    for (int off=1; off<16; off<<=1){
      #pragma unroll
      for (int r=0; r<4; ++r) rsum[r] += __shfl_xor(rsum[r], off, 64);
    }
    #pragma unroll
    for (int r=0; r<4; ++r) l_run[r] = l_run[r]*alpha[r] + rsum[r];
    #pragma unroll
    for (int ds=0; ds<4; ++ds)
      #pragma unroll
      for (int r=0; r<4; ++r){ aOr[ds][r] *= alpha[r]; aOi[ds][r] *= alpha[r]; }

    #pragma unroll
    for (int step=0; step<2; ++step){
      bf16x8 pf = *(const bf16x8*)&sP[(w*16 + l15)*72 + step*32 + quad*8];
      const int ro = (step==0) ? rd0 : rd1;
      #pragma unroll
      for (int ds=0; ds<4; ++ds){
        aOr[ds] = __builtin_amdgcn_mfma_f32_16x16x32_bf16(pf, *(const bf16x8*)&sVr[ds*1024 + ro], aOr[ds], 0,0,0);
        aOi[ds] = __builtin_amdgcn_mfma_f32_16x16x32_bf16(pf, *(const bf16x8*)&sVi[ds*1024 + ro], aOi[ds], 0,0,0);
      }
    }
  }

  #pragma unroll
  for (int r=0; r<4; ++r){
    const float il = 1.0f / l_run[r];
    const size_t ob = ((size_t)(b*Lq) + qt*64 + w*16 + quad*4 + r)*Dq + h*HDq;
    #pragma unroll
    for (int ds=0; ds<4; ++ds){
      Or[ob + ds*16 + l15] = f2us(aOr[ds][r] * il);
      Oi[ob + ds*16 + l15] = f2us(aOi[ds][r] * il);
    }
  }
}

// ---------------- launch ----------------
extern "C" void kernel_launch(void* const* d_in, const int* in_sizes, int n_in,
                              void* d_out, int out_size, void* d_ws, size_t ws_size,
                              hipStream_t stream)
{
  const float* x_r    = (const float*)d_in[0];
  const float* x_i    = (const float*)d_in[1];
  const float* Wq_r   = (const float*)d_in[2];
  const float* Wq_i   = (const float*)d_in[3];
  const float* Wk_r   = (const float*)d_in[4];
  const float* Wk_i   = (const float*)d_in[5];
  const float* Wv_r   = (const float*)d_in[6];
  const float* Wv_i   = (const float*)d_in[7];
  const float* Wo_r   = (const float*)d_in[8];
  const float* Wo_i   = (const float*)d_in[9];
  const float* bo_r   = (const float*)d_in[10];
  const float* bo_i   = (const float*)d_in[11];
  const float* ln1_gr = (const float*)d_in[12];
  const float* ln1_gi = (const float*)d_in[13];
  const float* ln1_br = (const float*)d_in[14];
  const float* ln1_bi = (const float*)d_in[15];
  const float* ln2_gr = (const float*)d_in[16];
  const float* ln2_gi = (const float*)d_in[17];
  const float* ln2_br = (const float*)d_in[18];
  const float* ln2_bi = (const float*)d_in[19];
  const float* W1_r   = (const float*)d_in[20];
  const float* W1_i   = (const float*)d_in[21];
  const float* b1_r   = (const float*)d_in[22];
  const float* b1_i   = (const float*)d_in[23];
  const float* W2_r   = (const float*)d_in[24];
  const float* W2_i   = (const float*)d_in[25];
  const float* b2_r   = (const float*)d_in[26];
  const float* b2_i   = (const float*)d_in[27];
  const float* mod_b  = (const float*)d_in[28];

  char* wsb = (char*)d_ws;
  const size_t MB = 1024*1024;
  // --- weights: 0..80 MB ---
  unsigned short* bWq_r = (unsigned short*)(wsb + 0*MB);
  unsigned short* bWq_i = (unsigned short*)(wsb + 2*MB);
  unsigned short* bWk_r = (unsigned short*)(wsb + 4*MB);
  unsigned short* bWk_i = (unsigned short*)(wsb + 6*MB);
  unsigned short* bWv_r = (unsigned short*)(wsb + 8*MB);
  unsigned short* bWv_i = (unsigned short*)(wsb + 10*MB);
  unsigned short* bWo_r = (unsigned short*)(wsb + 12*MB);
  unsigned short* bWo_i = (unsigned short*)(wsb + 14*MB);
  unsigned short* W1cat = (unsigned short*)(wsb + 16*MB);   // [8192,2048] = 32 MB
  unsigned short* W2cat = (unsigned short*)(wsb + 48*MB);   // [2048,8192] = 32 MB
  // --- activations: 80..120 MB ---
  unsigned short* hr  = (unsigned short*)(wsb + 80*MB);
  unsigned short* hi_ = (unsigned short*)(wsb + 84*MB);
  unsigned short* Qr  = (unsigned short*)(wsb + 88*MB);
  unsigned short* Qi  = (unsigned short*)(wsb + 92*MB);
  unsigned short* Kr  = (unsigned short*)(wsb + 96*MB);
  unsigned short* Ki  = (unsigned short*)(wsb + 100*MB);
  unsigned short* Vr  = (unsigned short*)(wsb + 104*MB);
  unsigned short* Vi  = (unsigned short*)(wsb + 108*MB);
  unsigned short* VTr = (unsigned short*)(wsb + 112*MB);
  unsigned short* VTi = (unsigned short*)(wsb + 116*MB);
  unsigned short* Or  = hr;                                 // hr/hi dead after QKV gemms
  unsigned short* Oi  = hi_;
  unsigned short* h2  = (unsigned short*)(wsb + 80*MB);     // augmented [M,2048], over O (dead after Wo)
  unsigned short* f   = (unsigned short*)(wsb + 88*MB);     // interleaved [M,8192] = 32 MB over Q/K/V/VT

  float* outR = (float*)d_out;                              // ar lives here (f32)
  float* outI = outR + (size_t)Mq*Dq;

  const dim3 blk(256);
  const dim3 gD(Mq/64, Dq/64);     // 32 x 16

  const int nDD = Dq*Dq;
  cvt4_kernel<<<dim3(nDD/2048, 4), blk, 0, stream>>>(Wq_r, Wq_i, Wk_r, Wk_i,
      bWq_r, bWq_i, bWk_r, bWk_i, nDD);
  cvt4_kernel<<<dim3(nDD/2048, 4), blk, 0, stream>>>(Wv_r, Wv_i, Wo_r, Wo_i,
      bWv_r, bWv_i, bWo_r, bWo_i, nDD);
  w1cat_kernel<<<2048, blk, 0, stream>>>(W1_r, W1_i, W1cat);
  w2cat_kernel<<<2048, blk, 0, stream>>>(W2_r, W2_i, W2cat);

  // 1. ln1 (separate r/i out, stride 1024)
  cln_kernel<<<Mq, blk, 0, stream>>>(x_r, x_i, ln1_gr, ln1_gi, ln1_br, ln1_bi, hr, hi_, 1024);
  // 2. Q,K (fused RoPE), V projections
  cgemm_kernel<0,true ><<<gD, blk, 0, stream>>>(hr, hi_, bWq_r, bWq_i, Qr, Qi,
      nullptr, nullptr, nullptr, nullptr, Dq, Dq);
  cgemm_kernel<0,true ><<<gD, blk, 0, stream>>>(hr, hi_, bWk_r, bWk_i, Kr, Ki,
      nullptr, nullptr, nullptr, nullptr, Dq, Dq);
  cgemm_kernel<0,false><<<gD, blk, 0, stream>>>(hr, hi_, bWv_r, bWv_i, Vr, Vi,
      nullptr, nullptr, nullptr, nullptr, Dq, Dq);
  // 2b. V transpose
  vtrans_kernel<<<dim3(16, 32), blk, 0, stream>>>(Vr, Vi, VTr, VTi);
  // 3. flash attention (O over hr/hi)
  fattn_kernel<<<dim3(16, 32), blk, 0, stream>>>(Qr, Qi, Kr, Ki, VTr, VTi, Or, Oi);
  // 4. Wo + bias + residual(x) -> d_out (f32)
  cgemm_kernel<1,false><<<gD, blk, 0, stream>>>(Or, Oi, bWo_r, bWo_i, outR, outI,
      bo_r, bo_i, x_r, x_i, Dq, Dq);
  // 5. ln2 -> h2 augmented [M,2048]
  cln_kernel<<<Mq, blk, 0, stream>>>(outR, outI, ln2_gr, ln2_gi, ln2_br, ln2_bi,
      h2, h2 + 1024, 2048);
  // 6. W1 (real GEMM, K'=2048, N'=8192) + ModReLU -> f interleaved
  rgemm_kernel<2,128><<<dim3(Mq/128, 8192/128), blk, 0, stream>>>(
      h2, W1cat, f, nullptr, b1_r, b1_i, nullptr, nullptr, mod_b, 8192, 2048);
  // 7. W2 (real GEMM, K'=8192, N'=2048) + bias + residual(d_out) -> d_out
  rgemm_kernel<1,64><<<dim3(Mq/64, 2048/128), blk, 0, stream>>>(
      f, W2cat, outR, outI, b2_r, b2_i, outR, outI, nullptr, 2048, 8192);
}